// Round 1
// baseline (991.195 us; speedup 1.0000x reference)
//
#include <hip/hip_runtime.h>
#include <hip/hip_bf16.h>

// Qwen3 MoE block: T=8192 tokens, H=1024, I=512, E=32, top-4.
// Pipeline: router -> scan -> build lists -> gate/up GEMM (+SiLU) -> down GEMM
//           (scaled by routing weight) -> gather-combine into d_out.

#define T_TOK 8192
#define H_DIM 1024
#define I_DIM 512
#define E_NUM 32
#define K_TOP 4
#define NSLOT (T_TOK * K_TOP)  // exactly 32768 slots total

typedef __bf16 bf16_t;
typedef __bf16 bf16x8 __attribute__((ext_vector_type(8)));
typedef float floatx4 __attribute__((ext_vector_type(4)));

// ---------------- Router: one block per token ----------------
__global__ __launch_bounds__(256) void router_kernel(
    const float* __restrict__ x, const float* __restrict__ gate_w,
    int* __restrict__ counts, int* __restrict__ topk_idx,
    float* __restrict__ topk_wt) {
  __shared__ float sx[H_DIM];
  __shared__ float slog[E_NUM];
  int t = blockIdx.x;
  const float* xr = x + (size_t)t * H_DIM;
  for (int i = threadIdx.x; i < H_DIM / 4; i += 256)
    ((float4*)sx)[i] = ((const float4*)xr)[i];
  __syncthreads();

  int e = threadIdx.x >> 3;  // 32 experts x 8 threads
  int p = threadIdx.x & 7;
  const float* gw = gate_w + (size_t)e * H_DIM;
  float acc = 0.f;
  for (int h = p; h < H_DIM; h += 8) acc += sx[h] * gw[h];
  acc += __shfl_xor(acc, 1);
  acc += __shfl_xor(acc, 2);
  acc += __shfl_xor(acc, 4);
  if (p == 0) slog[e] = acc;
  __syncthreads();

  if (threadIdx.x == 0) {
    float v[E_NUM];
    for (int i = 0; i < E_NUM; i++) v[i] = slog[i];
    int idx[K_TOP];
    float val[K_TOP];
    for (int k = 0; k < K_TOP; k++) {
      int bi = 0;
      float bv = -1e30f;
      for (int i = 0; i < E_NUM; i++)
        if (v[i] > bv) { bv = v[i]; bi = i; }
      idx[k] = bi; val[k] = bv; v[bi] = -1e30f;
    }
    // softmax denom cancels under top-k renorm: w_k = exp(l_k-m)/sum_top4
    float m = val[0], s = 0.f, w[K_TOP];
    for (int k = 0; k < K_TOP; k++) { w[k] = __expf(val[k] - m); s += w[k]; }
    float inv = 1.f / s;
    for (int k = 0; k < K_TOP; k++) {
      topk_idx[t * K_TOP + k] = idx[k];
      topk_wt[t * K_TOP + k] = w[k] * inv;
      atomicAdd(&counts[idx[k]], 1);
    }
  }
}

__global__ void scan_kernel(const int* __restrict__ counts,
                            int* __restrict__ offsets) {
  if (threadIdx.x == 0 && blockIdx.x == 0) {
    int acc = 0;
    for (int e = 0; e < E_NUM; e++) { offsets[e] = acc; acc += counts[e]; }
    offsets[E_NUM] = acc;
  }
}

__global__ __launch_bounds__(256) void build_kernel(
    const int* __restrict__ topk_idx, const float* __restrict__ topk_wt,
    const int* __restrict__ offsets, int* __restrict__ cursors,
    int* __restrict__ token_list, float* __restrict__ slot_wt,
    int* __restrict__ slot_of) {
  int t = blockIdx.x * 256 + threadIdx.x;
  if (t >= T_TOK) return;
  for (int k = 0; k < K_TOP; k++) {
    int e = topk_idx[t * K_TOP + k];
    int pos = atomicAdd(&cursors[e], 1);
    int slot = offsets[e] + pos;
    token_list[slot] = t;
    slot_wt[slot] = topk_wt[t * K_TOP + k];
    slot_of[t * K_TOP + k] = slot;
  }
}

// ---------------- GEMM tiles: 64x64x(BK=32), 4 waves, mfma 16x16x32 ----------
#define BM 64
#define BN 64
#define BK 32
#define LDK 40  // BK+8 pad: 80B row stride -> even 16B-group distribution

__global__ __launch_bounds__(256) void gateup_kernel(
    const float* __restrict__ x, const float* __restrict__ w_gate,
    const float* __restrict__ w_up, const int* __restrict__ counts,
    const int* __restrict__ offsets, const int* __restrict__ token_list,
    bf16_t* __restrict__ hbuf) {
  int e = blockIdx.z;
  int cnt = counts[e];
  int m_base = blockIdx.x * BM;
  if (m_base >= cnt) return;
  int n_base = blockIdx.y * BN;
  int off = offsets[e];

  __shared__ bf16_t sA[BM][LDK];
  __shared__ bf16_t sBg[BN][LDK];
  __shared__ bf16_t sBu[BN][LDK];
  __shared__ int sTok[BM];

  int tid = threadIdx.x;
  if (tid < BM) {
    int s = m_base + tid;
    sTok[tid] = (s < cnt) ? token_list[off + s] : -1;
  }
  __syncthreads();

  int lane = tid & 63;
  int wv = tid >> 6;
  int wm = (wv >> 1) * 32;
  int wn = (wv & 1) * 32;
  int l15 = lane & 15;
  int q = lane >> 4;

  floatx4 zero = {0.f, 0.f, 0.f, 0.f};
  floatx4 ag[2][2], au[2][2];
  for (int i = 0; i < 2; i++)
    for (int j = 0; j < 2; j++) { ag[i][j] = zero; au[i][j] = zero; }

  int ar = tid >> 2;        // A stage: row 0..63
  int ac = (tid & 3) * 8;   // 8-elem col chunk
  int bn = tid & 63;        // B stage: column (coalesced across lanes)
  int bk = (tid >> 6) * 8;  // 8 k-rows per thread

  const float* wg_base = w_gate + (size_t)e * H_DIM * I_DIM + n_base + bn;
  const float* wu_base = w_up + (size_t)e * H_DIM * I_DIM + n_base + bn;

  for (int k0 = 0; k0 < H_DIM; k0 += BK) {
    {  // stage A (gathered tokens, fp32 -> bf16)
      int tok = sTok[ar];
      float v[8];
      if (tok >= 0) {
        const float* src = x + (size_t)tok * H_DIM + k0 + ac;
        float4 f0 = ((const float4*)src)[0];
        float4 f1 = ((const float4*)src)[1];
        v[0] = f0.x; v[1] = f0.y; v[2] = f0.z; v[3] = f0.w;
        v[4] = f1.x; v[5] = f1.y; v[6] = f1.z; v[7] = f1.w;
      } else {
        for (int j = 0; j < 8; j++) v[j] = 0.f;
      }
      bf16x8 b;
      for (int j = 0; j < 8; j++) b[j] = (bf16_t)v[j];
      *(bf16x8*)&sA[ar][ac] = b;
    }
    {  // stage B gate & up, transposed into [n][k]
      bf16x8 bg, bu;
      const float* pg = wg_base + (size_t)(k0 + bk) * I_DIM;
      const float* pu = wu_base + (size_t)(k0 + bk) * I_DIM;
#pragma unroll
      for (int j = 0; j < 8; j++) {
        bg[j] = (bf16_t)pg[(size_t)j * I_DIM];
        bu[j] = (bf16_t)pu[(size_t)j * I_DIM];
      }
      *(bf16x8*)&sBg[bn][bk] = bg;
      *(bf16x8*)&sBu[bn][bk] = bu;
    }
    __syncthreads();

    bf16x8 af[2], bgf[2], buf_[2];
#pragma unroll
    for (int mi = 0; mi < 2; mi++)
      af[mi] = *(bf16x8*)&sA[wm + mi * 16 + l15][q * 8];
#pragma unroll
    for (int ni = 0; ni < 2; ni++) {
      bgf[ni] = *(bf16x8*)&sBg[wn + ni * 16 + l15][q * 8];
      buf_[ni] = *(bf16x8*)&sBu[wn + ni * 16 + l15][q * 8];
    }
#pragma unroll
    for (int mi = 0; mi < 2; mi++)
#pragma unroll
      for (int ni = 0; ni < 2; ni++) {
        ag[mi][ni] = __builtin_amdgcn_mfma_f32_16x16x32_bf16(
            af[mi], bgf[ni], ag[mi][ni], 0, 0, 0);
        au[mi][ni] = __builtin_amdgcn_mfma_f32_16x16x32_bf16(
            af[mi], buf_[ni], au[mi][ni], 0, 0, 0);
      }
    __syncthreads();
  }

  // epilogue: h = silu(g)*u -> bf16. C layout: col=lane&15, row=q*4+reg.
#pragma unroll
  for (int mi = 0; mi < 2; mi++)
#pragma unroll
    for (int ni = 0; ni < 2; ni++)
#pragma unroll
      for (int r = 0; r < 4; r++) {
        int row = wm + mi * 16 + q * 4 + r;
        int col = wn + ni * 16 + l15;
        if (m_base + row < cnt) {
          float g = ag[mi][ni][r];
          float u = au[mi][ni][r];
          float hv = g * (1.f / (1.f + __expf(-g))) * u;
          hbuf[(size_t)(off + m_base + row) * I_DIM + n_base + col] =
              (bf16_t)hv;
        }
      }
}

template <bool ATOMIC>
__global__ __launch_bounds__(256) void down_kernel(
    const bf16_t* __restrict__ hbuf, const float* __restrict__ w_down,
    const int* __restrict__ counts, const int* __restrict__ offsets,
    const float* __restrict__ slot_wt, const int* __restrict__ token_list,
    bf16_t* __restrict__ ybuf, float* __restrict__ out) {
  int e = blockIdx.z;
  int cnt = counts[e];
  int m_base = blockIdx.x * BM;
  if (m_base >= cnt) return;
  int n_base = blockIdx.y * BN;
  int off = offsets[e];

  __shared__ bf16_t sA[BM][LDK];
  __shared__ bf16_t sB[BN][LDK];
  __shared__ float sW[BM];
  __shared__ int sTok[BM];

  int tid = threadIdx.x;
  if (tid < BM) {
    int s = m_base + tid;
    bool v = (s < cnt);
    sW[tid] = v ? slot_wt[off + s] : 0.f;
    sTok[tid] = v ? token_list[off + s] : 0;
  }
  __syncthreads();

  int lane = tid & 63;
  int wv = tid >> 6;
  int wm = (wv >> 1) * 32;
  int wn = (wv & 1) * 32;
  int l15 = lane & 15;
  int q = lane >> 4;

  floatx4 zero = {0.f, 0.f, 0.f, 0.f};
  floatx4 acc[2][2];
  for (int i = 0; i < 2; i++)
    for (int j = 0; j < 2; j++) acc[i][j] = zero;

  int ar = tid >> 2;
  int ac = (tid & 3) * 8;
  int bn = tid & 63;
  int bk = (tid >> 6) * 8;

  const float* wd_base = w_down + (size_t)e * I_DIM * H_DIM + n_base + bn;

  for (int k0 = 0; k0 < I_DIM; k0 += BK) {
    {  // stage A from hbuf (already bf16)
      bf16x8 a;
      if (m_base + ar < cnt) {
        a = *(const bf16x8*)&hbuf[(size_t)(off + m_base + ar) * I_DIM + k0 + ac];
      } else {
        for (int j = 0; j < 8; j++) a[j] = (bf16_t)0.f;
      }
      *(bf16x8*)&sA[ar][ac] = a;
    }
    {  // stage B transposed
      bf16x8 b;
      const float* pd = wd_base + (size_t)(k0 + bk) * H_DIM;
#pragma unroll
      for (int j = 0; j < 8; j++) b[j] = (bf16_t)pd[(size_t)j * H_DIM];
      *(bf16x8*)&sB[bn][bk] = b;
    }
    __syncthreads();

    bf16x8 af[2], bf[2];
#pragma unroll
    for (int mi = 0; mi < 2; mi++)
      af[mi] = *(bf16x8*)&sA[wm + mi * 16 + l15][q * 8];
#pragma unroll
    for (int ni = 0; ni < 2; ni++)
      bf[ni] = *(bf16x8*)&sB[wn + ni * 16 + l15][q * 8];
#pragma unroll
    for (int mi = 0; mi < 2; mi++)
#pragma unroll
      for (int ni = 0; ni < 2; ni++)
        acc[mi][ni] = __builtin_amdgcn_mfma_f32_16x16x32_bf16(
            af[mi], bf[ni], acc[mi][ni], 0, 0, 0);
    __syncthreads();
  }

#pragma unroll
  for (int mi = 0; mi < 2; mi++)
#pragma unroll
    for (int ni = 0; ni < 2; ni++)
#pragma unroll
      for (int r = 0; r < 4; r++) {
        int row = wm + mi * 16 + q * 4 + r;
        int col = wn + ni * 16 + l15;
        if (m_base + row < cnt) {
          float v = acc[mi][ni][r] * sW[row];
          if (ATOMIC) {
            atomicAdd(&out[(size_t)sTok[row] * H_DIM + n_base + col], v);
          } else {
            ybuf[(size_t)(off + m_base + row) * H_DIM + n_base + col] =
                (bf16_t)v;
          }
        }
      }
}

__global__ __launch_bounds__(256) void gather_kernel(
    const bf16_t* __restrict__ ybuf, const int* __restrict__ slot_of,
    float* __restrict__ out) {
  int g = blockIdx.x * 256 + threadIdx.x;  // one 8-elem group
  int t = g >> 7;                          // H/8 = 128 groups per token
  int c = (g & 127) * 8;
  float acc[8];
#pragma unroll
  for (int j = 0; j < 8; j++) acc[j] = 0.f;
#pragma unroll
  for (int k = 0; k < K_TOP; k++) {
    int slot = slot_of[t * K_TOP + k];
    bf16x8 yv = *(const bf16x8*)&ybuf[(size_t)slot * H_DIM + c];
#pragma unroll
    for (int j = 0; j < 8; j++) acc[j] += (float)yv[j];
  }
  float4* o = (float4*)(out + (size_t)t * H_DIM + c);
  o[0] = make_float4(acc[0], acc[1], acc[2], acc[3]);
  o[1] = make_float4(acc[4], acc[5], acc[6], acc[7]);
}

extern "C" void kernel_launch(void* const* d_in, const int* in_sizes, int n_in,
                              void* d_out, int out_size, void* d_ws,
                              size_t ws_size, hipStream_t stream) {
  const float* x = (const float*)d_in[0];
  const float* gate_w = (const float*)d_in[1];
  const float* w_gate = (const float*)d_in[2];
  const float* w_up = (const float*)d_in[3];
  const float* w_down = (const float*)d_in[4];
  float* out = (float*)d_out;

  char* ws = (char*)d_ws;
  int* counts = (int*)(ws + 0);
  int* cursors = (int*)(ws + 128);
  int* offsets = (int*)(ws + 256);
  int* topk_idx = (int*)(ws + 512);
  float* topk_wt = (float*)(ws + 512 + 131072);
  int* slot_of = (int*)(ws + 512 + 2 * 131072);
  int* token_list = (int*)(ws + 512 + 3 * 131072);
  float* slot_wt = (float*)(ws + 512 + 4 * 131072);
  const size_t H_BASE = 1ull << 20;
  const size_t H_BYTES = (size_t)NSLOT * I_DIM * 2;  // 32 MB bf16
  const size_t Y_BYTES = (size_t)NSLOT * H_DIM * 2;  // 64 MB bf16
  bf16_t* hbuf = (bf16_t*)(ws + H_BASE);
  bf16_t* ybuf = (bf16_t*)(ws + H_BASE + H_BYTES);

  bool gather_path = ws_size >= (H_BASE + H_BYTES + Y_BYTES);

  hipMemsetAsync(ws, 0, 512, stream);  // counts/cursors/offsets
  router_kernel<<<T_TOK, 256, 0, stream>>>(x, gate_w, counts, topk_idx,
                                           topk_wt);
  scan_kernel<<<1, 64, 0, stream>>>(counts, offsets);
  build_kernel<<<T_TOK / 256, 256, 0, stream>>>(
      topk_idx, topk_wt, offsets, cursors, token_list, slot_wt, slot_of);
  gateup_kernel<<<dim3(T_TOK / BM, I_DIM / BN, E_NUM), 256, 0, stream>>>(
      x, w_gate, w_up, counts, offsets, token_list, hbuf);
  if (gather_path) {
    down_kernel<false><<<dim3(T_TOK / BM, H_DIM / BN, E_NUM), 256, 0, stream>>>(
        hbuf, w_down, counts, offsets, slot_wt, token_list, ybuf, out);
    gather_kernel<<<(T_TOK * (H_DIM / 8)) / 256, 256, 0, stream>>>(
        ybuf, slot_of, out);
  } else {
    hipMemsetAsync(out, 0, (size_t)out_size * sizeof(float), stream);
    down_kernel<true><<<dim3(T_TOK / BM, H_DIM / BN, E_NUM), 256, 0, stream>>>(
        hbuf, w_down, counts, offsets, slot_wt, token_list, ybuf, out);
  }
}